// Round 6
// baseline (381.214 us; speedup 1.0000x reference)
//
#include <hip/hip_runtime.h>
#include <stdint.h>

#define NE 50000   // entities
#define DD 128     // dim
#define RR 16      // relations
#define EE 50000   // edges per relation
#define NT 64      // node tile per block
#define NTOT (RR * NE)                 // 800000 flat (n,r) keys, node-major
#define SCAN_BLK 4096
#define NSCAN ((NTOT + SCAN_BLK - 1) / SCAN_BLK)   // 196
#define EDCAP 2048                     // LDS edge-slice capacity (mean 1024, sigma 32)

typedef short  shortx8 __attribute__((ext_vector_type(8)));
typedef short  shortx4 __attribute__((ext_vector_type(4)));
typedef float  floatx4 __attribute__((ext_vector_type(4)));

__device__ __forceinline__ unsigned short f2bf(float f) {
    unsigned u = __float_as_uint(f);
    u += 0x7fffu + ((u >> 16) & 1u);   // RNE
    return (unsigned short)(u >> 16);
}
__device__ __forceinline__ float bf2f(unsigned short h) {
    return __uint_as_float(((unsigned)h) << 16);
}

// ---- fused init: rel_trans -> fragment-ordered bf16 Tf | ent_emb -> bf16 | histogram+rank
// Tf: element T[r][row][k] at ((((r*8+(row>>4))*4+(k>>5))*64) + ((k>>3)&3)*16 + (row&15))*8 + (k&7)
#define TB 128
#define EB 6250
#define HB 782
__global__ void prep_k(const float* __restrict__ rt, unsigned short* __restrict__ Tf,
                       const float4* __restrict__ emb, shortx4* __restrict__ embA,
                       const int* __restrict__ erow, int* __restrict__ counts,
                       uchar4* __restrict__ rank) {
    int b = blockIdx.x, t = threadIdx.x;
    if (b < TB) {
        int c = b * 256 + t;                 // chunk: 8 consecutive k of one (r,row)
        int r = c >> 11, row = (c >> 4) & 127, cb = c & 15;
        int kt = cb >> 2, qq = cb & 3, rg = row >> 4, m = row & 15;
        const float4* src = (const float4*)(rt + (size_t)c * 8);
        float4 v0 = src[0], v1 = src[1];
        shortx8 w;
        w[0] = (short)f2bf(v0.x); w[1] = (short)f2bf(v0.y);
        w[2] = (short)f2bf(v0.z); w[3] = (short)f2bf(v0.w);
        w[4] = (short)f2bf(v1.x); w[5] = (short)f2bf(v1.y);
        w[6] = (short)f2bf(v1.z); w[7] = (short)f2bf(v1.w);
        size_t idx = ((((size_t)r * 8 + rg) * 4 + kt) * 64 + qq * 16 + m) * 8;
        *(shortx8*)(Tf + idx) = w;
    } else if (b < TB + EB) {
        int i = (b - TB) * 256 + t;
        if (i < NE * DD / 4) {
            float4 v = emb[i];
            shortx4 w;
            w[0] = (short)f2bf(v.x); w[1] = (short)f2bf(v.y);
            w[2] = (short)f2bf(v.z); w[3] = (short)f2bf(v.w);
            embA[i] = w;
        }
    } else {
        int e4 = (b - TB - EB) * 256 + t;
        if (e4 < RR * EE / 4) {
            int r  = e4 / (EE / 4);
            int i4 = e4 - r * (EE / 4);
            int4 rw = *(const int4*)(erow + (size_t)r * EE + i4 * 4);
            uchar4 rk;
            rk.x = (unsigned char)atomicAdd(&counts[rw.x * RR + r], 1);
            rk.y = (unsigned char)atomicAdd(&counts[rw.y * RR + r], 1);
            rk.z = (unsigned char)atomicAdd(&counts[rw.z * RR + r], 1);
            rk.w = (unsigned char)atomicAdd(&counts[rw.w * RR + r], 1);
            rank[(size_t)r * (EE / 4) + i4] = rk;
        }
    }
}

__global__ void scanA(const int* __restrict__ c, int* __restrict__ bsum) {
    int b = blockIdx.x, t = threadIdx.x;
    int base = b * SCAN_BLK + t * 16;
    int s = 0;
    #pragma unroll
    for (int i = 0; i < 16; i++) {
        int idx = base + i;
        if (idx < NTOT) s += c[idx];
    }
    __shared__ int sh[256];
    sh[t] = s;
    __syncthreads();
    for (int off = 128; off > 0; off >>= 1) {
        if (t < off) sh[t] += sh[t + off];
        __syncthreads();
    }
    if (t == 0) bsum[b] = sh[0];
}

// scanC derives its own block prefix from raw bsum (scanB folded in).
__global__ void scanC(const int* __restrict__ counts, int* __restrict__ rp,
                      const int* __restrict__ bsum) {
    int b = blockIdx.x, t = threadIdx.x;
    __shared__ int shb[256];
    shb[t] = (t < NSCAN) ? bsum[t] : 0;
    __syncthreads();
    for (int off = 1; off < 256; off <<= 1) {
        int add = (t >= off) ? shb[t - off] : 0;
        __syncthreads();
        shb[t] += add;
        __syncthreads();
    }
    int blockPrefix = (b > 0) ? shb[b - 1] : 0;
    int base = b * SCAN_BLK + t * 16;
    int vals[16];
    int s = 0;
    #pragma unroll
    for (int i = 0; i < 16; i++) {
        int idx = base + i;
        vals[i] = (idx < NTOT) ? counts[idx] : 0;
        s += vals[i];
    }
    __shared__ int sh[256];
    sh[t] = s;
    __syncthreads();
    for (int off = 1; off < 256; off <<= 1) {
        int add = (t >= off) ? sh[t - off] : 0;
        __syncthreads();
        sh[t] += add;
        __syncthreads();
    }
    int run = blockPrefix + sh[t] - s;
    #pragma unroll
    for (int i = 0; i < 16; i++) {
        int idx = base + i;
        if (idx < NTOT) {
            rp[idx] = run;
            run += vals[i];
            if (idx == NTOT - 1) rp[NTOT] = run;
        }
    }
}

// atomic-free placement: pos = rp[key] + saved rank
__global__ void fill_k(const int* __restrict__ erow, const int* __restrict__ ecol,
                       const float* __restrict__ eval, const int* __restrict__ rp,
                       const uchar4* __restrict__ rank, int2* __restrict__ edges) {
    int r  = blockIdx.y;
    int i4 = blockIdx.x * 256 + threadIdx.x;
    if (i4 < EE / 4) {
        int4   rw = *(const int4*)(erow + (size_t)r * EE + i4 * 4);
        int4   cl = *(const int4*)(ecol + (size_t)r * EE + i4 * 4);
        float4 vl = *(const float4*)(eval + (size_t)r * EE + i4 * 4);
        uchar4 rk = rank[(size_t)r * (EE / 4) + i4];
        edges[rp[rw.x * RR + r] + rk.x] = make_int2(cl.x, __float_as_int(vl.x));
        edges[rp[rw.y * RR + r] + rk.y] = make_int2(cl.y, __float_as_int(vl.y));
        edges[rp[rw.z * RR + r] + rk.z] = make_int2(cl.z, __float_as_int(vl.z));
        edges[rp[rw.w * RR + r] + rk.w] = make_int2(cl.w, __float_as_int(vl.w));
    }
}

__device__ __forceinline__ void accum_chunks(float a0[8], float a1[8], float v,
                                             shortx8 c0, shortx8 c1) {
    #pragma unroll
    for (int j = 0; j < 8; j++) {
        a0[j] = fmaf(v, bf2f((unsigned short)c0[j]), a0[j]);
        a1[j] = fmaf(v, bf2f((unsigned short)c1[j]), a1[j]);
    }
}

// Fused layer v3. 256 threads = 4 waves, 64-node tile, grid 782.
// Startup: block's contiguous rp slice (1025 ints) + contiguous edge slice (~1024) -> LDS.
// Per relation r: phase A consumes prefetched emb rows (r) + tail -> pack -> Bt;
// phase B reads rp/edges for r+1 from LDS (no global chain), issues emb(r+1) loads,
// then MFMA(r) with A-frags streamed from L2-resident fragment-ordered Tf.
template<bool FINAL>
__global__ __launch_bounds__(256, 3)
void layer_k(const unsigned short* __restrict__ embIn,
             const unsigned short* __restrict__ Tf,
             const int* __restrict__ rp,
             const int2* __restrict__ eg,
             unsigned short* __restrict__ embOut,
             float* __restrict__ outF)
{
    __shared__ __align__(16) unsigned short Bt[64 * 128];   // 16 KB
    __shared__ int  rpL[NT * RR + 1];                       // 4.1 KB
    __shared__ int2 edL[EDCAP];                             // 16 KB
    __shared__ float ssred[4][64];

    const int t    = threadIdx.x;
    const int lane = t & 63;
    const int w    = t >> 6;      // 0..3: i block (x32)
    const int colq = lane & 15;
    const int q    = lane >> 4;
    const int n0   = blockIdx.x * NT;
    const int nsub = t >> 3;      // node within pass (0..31)
    const int dgrp = t & 7;       // dim chunks dgrp, dgrp+8
    const int base = n0 * RR;

    // ---- startup staging: rp slice + edge slice -> LDS
    const int sBase = rp[base];
    const int sEnd  = rp[(base + NT * RR < NTOT) ? base + NT * RR : NTOT];
    #pragma unroll
    for (int i = 0; i < 5; i++) {
        int idx = i * 256 + t;
        if (idx <= NT * RR) {
            int gi = base + idx;
            rpL[idx] = rp[gi < NTOT ? gi : NTOT];
        }
    }
    {
        int cnt = sEnd - sBase;
        if (cnt > EDCAP) cnt = EDCAP;
        for (int i = t; i < cnt; i += 256) edL[i] = eg[sBase + i];
    }
    __syncthreads();

    auto getE = [&](int idx) -> int2 {
        int o = idx - sBase;
        return (o < EDCAP) ? edL[o] : eg[idx];
    };

    floatx4 acc[2][4];
    #pragma unroll
    for (int a = 0; a < 2; a++)
        #pragma unroll
        for (int c = 0; c < 4; c++)
            acc[a][c] = (floatx4){0.f, 0.f, 0.f, 0.f};

    int   sC[2], cC[2];
    float v0C[2], v1C[2];
    shortx8 m[2][2][2];   // [p][edge][chunk] prefetched emb rows

    auto issueGather = [&](int r) {
        #pragma unroll
        for (int p = 0; p < 2; p++) {
            int li = (p * 32 + nsub) * RR + r;
            int s = rpL[li], e = rpL[li + 1];
            int c = e - s;
            int2 E0 = getE(s);
            int2 E1 = getE(s + 1);
            int col0 = c > 0 ? E0.x : 0;
            int col1 = c > 1 ? E1.x : 0;
            v0C[p] = c > 0 ? __int_as_float(E0.y) : 0.f;
            v1C[p] = c > 1 ? __int_as_float(E1.y) : 0.f;
            sC[p] = s; cC[p] = c;
            const unsigned short* r0 = embIn + (size_t)col0 * DD + dgrp * 8;
            const unsigned short* r1 = embIn + (size_t)col1 * DD + dgrp * 8;
            m[p][0][0] = *(const shortx8*)r0;
            m[p][0][1] = *(const shortx8*)(r0 + 64);
            m[p][1][0] = *(const shortx8*)r1;
            m[p][1][1] = *(const shortx8*)(r1 + 64);
        }
    };

    issueGather(0);   // prologue: one exposed chain

    #pragma unroll 1
    for (int r = 0; r < RR; r++) {
        // ---- phase A: consume m(r) + tail -> pack -> Bt
        #pragma unroll
        for (int p = 0; p < 2; p++) {
            float a0[8], a1[8];
            #pragma unroll
            for (int j = 0; j < 8; j++) { a0[j] = 0.f; a1[j] = 0.f; }
            accum_chunks(a0, a1, v0C[p], m[p][0][0], m[p][0][1]);
            accum_chunks(a0, a1, v1C[p], m[p][1][0], m[p][1][1]);
            if (cC[p] > 2) {
                #pragma unroll 1
                for (int k = sC[p] + 2; k < sC[p] + cC[p]; k++) {
                    int2 E = getE(k);
                    float v = __int_as_float(E.y);
                    const unsigned short* rw_ = embIn + (size_t)E.x * DD + dgrp * 8;
                    accum_chunks(a0, a1, v, *(const shortx8*)rw_, *(const shortx8*)(rw_ + 64));
                }
            }
            int nl = p * 32 + nsub;
            shortx8 w0, w1;
            #pragma unroll
            for (int j = 0; j < 8; j++) { w0[j] = (short)f2bf(a0[j]); w1[j] = (short)f2bf(a1[j]); }
            int pc = (dgrp ^ nl) & 7;
            *(shortx8*)&Bt[nl * 128 + pc * 8] = w0;
            *(shortx8*)&Bt[nl * 128 + (8 | pc) * 8] = w1;
        }
        __syncthreads();   // Bt(r) ready

        // ---- phase B: prefetch gather(r+1) from LDS metadata; then MFMA(r)
        if (r + 1 < RR) issueGather(r + 1);

        shortx8 afN[2];
        #pragma unroll
        for (int it2 = 0; it2 < 2; it2++)
            afN[it2] = *(const shortx8*)(Tf + ((((size_t)r * 8 + (w * 2 + it2)) * 4 + 0) * 64 + lane) * 8);
        #pragma unroll 1
        for (int kt = 0; kt < 4; kt++) {
            shortx8 afC[2];
            afC[0] = afN[0]; afC[1] = afN[1];
            if (kt < 3) {
                #pragma unroll
                for (int it2 = 0; it2 < 2; it2++)
                    afN[it2] = *(const shortx8*)(Tf + ((((size_t)r * 8 + (w * 2 + it2)) * 4 + (kt + 1)) * 64 + lane) * 8);
            }
            int lc = kt * 4 + q;
            shortx8 bfr[4];
            #pragma unroll
            for (int c = 0; c < 4; c++) {
                int nl = c * 16 + colq;
                int pc = (lc & 8) | ((lc ^ nl) & 7);
                bfr[c] = *(const shortx8*)&Bt[nl * 128 + pc * 8];
            }
            #pragma unroll
            for (int it2 = 0; it2 < 2; it2++)
                #pragma unroll
                for (int c = 0; c < 4; c++)
                    acc[it2][c] = __builtin_amdgcn_mfma_f32_16x16x32_bf16(afC[it2], bfr[c], acc[it2][c], 0, 0, 0);
        }
        __syncthreads();   // MFMA done with Bt
    }

    // ---- epilogue. D: col=lane&15 -> n, row=q*4+g -> i (within 16x16 tile)
    if (!FINAL) {
        #pragma unroll
        for (int c = 0; c < 4; c++) {
            int n = n0 + c * 16 + colq;
            if (n < NE) {
                #pragma unroll
                for (int it2 = 0; it2 < 2; it2++) {
                    shortx4 wv;
                    #pragma unroll
                    for (int g = 0; g < 4; g++) {
                        float v = acc[it2][c][g];
                        v = v > 0.f ? v : 0.f;
                        wv[g] = (short)f2bf(v);
                    }
                    *(shortx4*)(embOut + ((size_t)n * DD + w * 32 + it2 * 16 + q * 4)) = wv;
                }
            }
        }
    } else {
        #pragma unroll
        for (int c = 0; c < 4; c++) {
            float ss = 0.f;
            #pragma unroll
            for (int it2 = 0; it2 < 2; it2++)
                #pragma unroll
                for (int g = 0; g < 4; g++) {
                    float v = acc[it2][c][g];
                    v = v > 0.f ? v : 0.f;
                    acc[it2][c][g] = v;
                    ss += v * v;
                }
            ss += __shfl_xor(ss, 16, 64);   // reduce over q quads
            ss += __shfl_xor(ss, 32, 64);
            if (q == 0) ssred[w][c * 16 + colq] = ss;
        }
        __syncthreads();
        #pragma unroll
        for (int c = 0; c < 4; c++) {
            int nl = c * 16 + colq;
            float tot = ssred[0][nl] + ssred[1][nl] + ssred[2][nl] + ssred[3][nl];
            float scale = 1.f / fmaxf(sqrtf(tot), 1e-12f);
            int n = n0 + nl;
            if (n < NE) {
                #pragma unroll
                for (int it2 = 0; it2 < 2; it2++) {
                    floatx4 v4;
                    #pragma unroll
                    for (int g = 0; g < 4; g++) v4[g] = acc[it2][c][g] * scale;
                    *(floatx4*)(outF + ((size_t)n * DD + w * 32 + it2 * 16 + q * 4)) = v4;
                }
            }
        }
    }
}

static inline size_t align256(size_t x) { return (x + 255) & ~(size_t)255; }

extern "C" void kernel_launch(void* const* d_in, const int* in_sizes, int n_in,
                              void* d_out, int out_size, void* d_ws, size_t ws_size,
                              hipStream_t stream)
{
    const float* ent_emb   = (const float*)d_in[0];   // [NE, DD] fp32
    const float* rel_trans = (const float*)d_in[1];   // [RR, DD, DD] fp32
    const float* edge_val  = (const float*)d_in[2];   // [RR, EE] fp32
    const int*   edge_row  = (const int*)d_in[3];     // [RR, EE] int32
    const int*   edge_col  = (const int*)d_in[4];     // [RR, EE] int32
    float* out = (float*)d_out;                       // [NE, DD] fp32

    char* ws = (char*)d_ws;
    size_t off = 0;
    int* counts = (int*)(ws + off);  off = align256(off + (size_t)NTOT * 4);
    int* rpf    = (int*)(ws + off);  off = align256(off + ((size_t)NTOT + 1) * 4);
    int* bsum   = (int*)(ws + off);  off = align256(off + 256 * 4);
    uchar4* rank = (uchar4*)(ws + off); off = align256(off + (size_t)NTOT);
    int2* edges = (int2*)(ws + off); off = align256(off + ((size_t)NTOT + 8) * 8);  // +pad
    unsigned short* Tf   = (unsigned short*)(ws + off); off = align256(off + (size_t)RR * DD * DD * 2);
    unsigned short* embA = (unsigned short*)(ws + off); off = align256(off + (size_t)NE * DD * 2);
    unsigned short* embB = (unsigned short*)(ws + off); off = align256(off + (size_t)NE * DD * 2);
    // total ~40 MB

    hipMemsetAsync(counts, 0, (size_t)NTOT * 4, stream);
    prep_k<<<TB + EB + HB, 256, 0, stream>>>(rel_trans, Tf, (const float4*)ent_emb,
                                             (shortx4*)embA, edge_row, counts, rank);
    scanA<<<NSCAN, 256, 0, stream>>>(counts, bsum);
    scanC<<<NSCAN, 256, 0, stream>>>(counts, rpf, bsum);
    dim3 eg_grid((EE / 4 + 255) / 256, RR);
    fill_k<<<eg_grid, 256, 0, stream>>>(edge_row, edge_col, edge_val, rpf, rank, edges);

    int nb = (NE + NT - 1) / NT;  // 782
    layer_k<false><<<nb, 256, 0, stream>>>(embA, Tf, rpf, edges, embB, nullptr);
    layer_k<true ><<<nb, 256, 0, stream>>>(embB, Tf, rpf, edges, nullptr, out);
}